// Round 5
// baseline (109.466 us; speedup 1.0000x reference)
//
#include <hip/hip_runtime.h>
#include <hip/hip_bf16.h>

#define NC 20
#define NCELL 49
#define NGT 32
#define NIMG 8192
#define IPB 8                      // images per block
#define CPB (IPB * NCELL)          // 392 cells per block
#define NBLK (NIMG / IPB)          // 1024 blocks = exactly 4 resident per CU
#define LAMBDA_COORD 5.0f
#define LAMBDA_NOOBJ 0.5f
#define EPS_IOU 1e-6f

// Divide-free IoU argmax via S-form: S = pa + ga + eps. iou = in/(S-in) and
// x/(S-x) is monotone in in/S, so comparing in_j*bS > bin*S_j orders
// identically. Init (-1, 1) => j=0 always wins; strict > => first-index
// argmax (jnp semantics).
#define UPD(g, ga_, j_) do {                                          \
    float iw0 = fmaxf(fminf(px2_0, (g).z) - fmaxf(px1_0, (g).x), 0.f);\
    float ih0 = fmaxf(fminf(py2_0, (g).w) - fmaxf(py1_0, (g).y), 0.f);\
    float in0 = iw0 * ih0;                                            \
    float S0  = pa0e + (ga_);                                         \
    if (in0 * bS0 > bin0 * S0) { bin0 = in0; bS0 = S0; bi0 = (j_); }  \
    float iw1 = fmaxf(fminf(px2_1, (g).z) - fmaxf(px1_1, (g).x), 0.f);\
    float ih1 = fmaxf(fminf(py2_1, (g).w) - fmaxf(py1_1, (g).y), 0.f);\
    float in1 = iw1 * ih1;                                            \
    float S1  = pa1e + (ga_);                                         \
    if (in1 * bS1 > bin1 * S1) { bin1 = in1; bS1 = S1; bi1 = (j_); }  \
} while (0)

__global__ __launch_bounds__(256, 4) void yolo_main_kernel(
    const float* __restrict__ outputs,     // [N, 49, 30]
    const float* __restrict__ gt_boxes,    // [N, 32, 4]
    const int*   __restrict__ gt_labels,   // [N, 32]
    float* __restrict__ out)               // [1]
{
    __shared__ float4   s_act4[1920];      // 30720 B: up to 256 cells x 30 floats
    __shared__ float4   s_gtc[IPB * NGT];  //  4096 B: x1,y1,x2,y2 per GT
    __shared__ float    s_ga[IPB * NGT];   //  1024 B: area per GT
    __shared__ unsigned s_mask[IPB];
    __shared__ float    s_w[4];

    const int tid = threadIdx.x;

    if (tid < IPB) s_mask[tid] = 0u;
    __syncthreads();

    // ---- stage GT: exactly one record per thread (8 img x 32 gt = 256) ----
    {
        float4 b = reinterpret_cast<const float4*>(gt_boxes)[(size_t)blockIdx.x * 256 + tid];
        s_gtc[tid] = make_float4(fmaf(b.z, -0.5f, b.x), fmaf(b.w, -0.5f, b.y),
                                 fmaf(b.z,  0.5f, b.x), fmaf(b.w,  0.5f, b.y));
        s_ga[tid] = b.z * b.w;
        int lab = gt_labels[(size_t)blockIdx.x * 256 + tid];
        atomicOr(&s_mask[tid >> 5], 1u << lab);
    }
    // (GT-ready barrier is merged with the pass-1 staging barrier below)

    const float4* asrc = reinterpret_cast<const float4*>(outputs)
                       + (size_t)blockIdx.x * (CPB * 30 / 4);

    float partial = 0.f;

    // ---- two passes over one act buffer; SINGLE code instance of the body ----
    for (int pass = 0; pass < 2; ++pass) {
        const int nf4 = (pass == 0) ? 1920 : (CPB - 256) * 30 / 4;   // 1920 / 1020
        const float4* sp = asrc + pass * 1920;
        for (int i = tid; i < nf4; i += 256) s_act4[i] = sp[i];
        __syncthreads();

        const int c = pass * 256 + tid;                // cell index within block
        if (c < CPB) {
            const unsigned rel  = ((unsigned)c * 1339u) >> 16;   // c/49 for c<392
            const unsigned mask = s_mask[rel];
            const float2* a2 = reinterpret_cast<const float2*>(s_act4) + tid * 15;

            // ---- CE, streaming (NO per-thread array -> nothing to spill) ----
            float mx = -3.402823466e38f, sel = 0.f;
            #pragma unroll
            for (int k = 0; k < 10; ++k) {
                float2 v = a2[5 + k];
                mx  = fmaxf(mx, fmaxf(v.x, v.y));
                sel += ((mask >> (2 * k))     & 1u) ? v.x : 0.f;
                sel += ((mask >> (2 * k + 1)) & 1u) ? v.y : 0.f;
            }
            float ssum = 0.f;
            #pragma unroll
            for (int k = 0; k < 10; ++k) {
                float2 v = a2[5 + k];
                ssum += __expf(v.x - mx) + __expf(v.y - mx);
            }
            const float ce = (float)__popc(mask) * (mx + __logf(ssum)) - sel;

            // ---- box registers ----
            float2 q0 = a2[0], q1 = a2[1], q2 = a2[2], q3 = a2[3], q4 = a2[4];
            const float cx0 = q0.x, cy0 = q0.y, w0 = q1.x, h0 = q1.y, cf0 = q2.x;
            const float cx1 = q2.y, cy1 = q3.x, w1 = q3.y, h1 = q4.x, cf1 = q4.y;
            const float px1_0 = fmaf(w0, -0.5f, cx0), py1_0 = fmaf(h0, -0.5f, cy0);
            const float px2_0 = fmaf(w0,  0.5f, cx0), py2_0 = fmaf(h0,  0.5f, cy0);
            const float px1_1 = fmaf(w1, -0.5f, cx1), py1_1 = fmaf(h1, -0.5f, cy1);
            const float px2_1 = fmaf(w1,  0.5f, cx1), py2_1 = fmaf(h1,  0.5f, cy1);
            const float pa0e = w0 * h0 + EPS_IOU, pa1e = w1 * h1 + EPS_IOU;

            const float4* gtc = s_gtc + rel * NGT;
            const float*  gab = s_ga  + rel * NGT;
            float bin0 = -1.f, bS0 = 1.f, bin1 = -1.f, bS1 = 1.f;
            int bi0 = 0, bi1 = 0;
            #pragma unroll
            for (int jc = 0; jc < NGT; jc += 4) {
                float4 g0 = gtc[jc], g1 = gtc[jc + 1];
                float4 g2 = gtc[jc + 2], g3 = gtc[jc + 3];
                float4 ar = *reinterpret_cast<const float4*>(gab + jc);
                UPD(g0, ar.x, jc);
                UPD(g1, ar.y, jc + 1);
                UPD(g2, ar.z, jc + 2);
                UPD(g3, ar.w, jc + 3);
            }

            // ---- epilogue: recover matched cx/cy/w/h from corners ----
            float term0, term1;
            if (bin0 > 0.f) {
                float4 g = gtc[bi0];
                const float iou = __fdividef(bin0, bS0 - bin0);
                const float dx = cx0 - (g.x + g.z) * 0.5f;
                const float dy = cy0 - (g.y + g.w) * 0.5f;
                const float dw = sqrtf(w0) - sqrtf(g.z - g.x);
                const float dh = sqrtf(h0) - sqrtf(g.w - g.y);
                term0 = LAMBDA_COORD * (dx * dx + dy * dy + dw * dw + dh * dh)
                      + (cf0 - iou) * (cf0 - iou) + ce;
            } else {
                term0 = LAMBDA_NOOBJ * cf0 * cf0;
            }
            if (bin1 > 0.f) {
                float4 g = gtc[bi1];
                const float iou = __fdividef(bin1, bS1 - bin1);
                const float dx = cx1 - (g.x + g.z) * 0.5f;
                const float dy = cy1 - (g.y + g.w) * 0.5f;
                const float dw = sqrtf(w1) - sqrtf(g.z - g.x);
                const float dh = sqrtf(h1) - sqrtf(g.w - g.y);
                term1 = LAMBDA_COORD * (dx * dx + dy * dy + dw * dw + dh * dh)
                      + (cf1 - iou) * (cf1 - iou) + ce;
            } else {
                term1 = LAMBDA_NOOBJ * cf1 * cf1;
            }
            partial += term0 + term1;
        }
        __syncthreads();   // all reads of s_act4 done before next pass restages
    }

    // ---- block reduce -> one atomic per block ----
    #pragma unroll
    for (int off = 32; off > 0; off >>= 1)
        partial += __shfl_down(partial, off);
    if ((tid & 63) == 0) s_w[tid >> 6] = partial;
    __syncthreads();
    if (tid == 0)
        atomicAdd(out, (s_w[0] + s_w[1] + s_w[2] + s_w[3]) * (1.0f / (float)NIMG));
}

extern "C" void kernel_launch(void* const* d_in, const int* in_sizes, int n_in,
                              void* d_out, int out_size, void* d_ws, size_t ws_size,
                              hipStream_t stream) {
    const float* outputs   = (const float*)d_in[0];
    const float* gt_boxes  = (const float*)d_in[1];
    const int*   gt_labels = (const int*)d_in[2];
    float* out = (float*)d_out;

    hipMemsetAsync(out, 0, sizeof(float), stream);
    yolo_main_kernel<<<NBLK, 256, 0, stream>>>(outputs, gt_boxes, gt_labels, out);
}

// Round 6
// 32.065 us; speedup vs baseline: 3.4139x; 3.4139x over previous
//
#include <hip/hip_runtime.h>
#include <hip/hip_bf16.h>

#define NC 20
#define NCELL 49
#define NGT 32
#define NIMG 8192
#define NTOT (NIMG * NCELL)        // 401408
#define CPB 128                    // cells per block (256 threads = 128 cells x 2 boxes)
#define NBLK (NTOT / CPB)          // 3136 blocks, exact
#define NSPAN 4                    // images spanned by 128 consecutive cells (<= 4)
#define LAMBDA_COORD 5.0f
#define LAMBDA_NOOBJ 0.5f
#define EPS_IOU 1e-6f

// Thread = (cell, box). Small live set (one box), full occupancy target.
// S-form argmax: S = pa+ga+eps; in/(S-in) monotone in in/S, so
// in_j*bS > bin*S_j orders identically to IoU. Init (-1,1): j=0 always wins,
// strict > => first-index argmax (jnp semantics).
__global__ __launch_bounds__(256, 8) void yolo_main_kernel(
    const float* __restrict__ outputs,     // [N, 49, 30]
    const float* __restrict__ gt_boxes,    // [N, 32, 4]
    const int*   __restrict__ gt_labels,   // [N, 32]
    float* __restrict__ partials)          // [NBLK]
{
    __shared__ float4   s_act4[CPB * 30 / 4];    // 960 float4 = 15360 B
    __shared__ float4   s_gtc[NSPAN * NGT];      // 2048 B: x1,y1,x2,y2
    __shared__ float    s_ga [NSPAN * NGT];      //  512 B: gt area
    __shared__ unsigned s_mask[NSPAN];
    __shared__ float    s_w[4];

    const int tid = threadIdx.x;
    const unsigned base   = blockIdx.x * CPB;        // first cell of block
    const unsigned img_lo = base / NCELL;            // scalar magic-div
    const unsigned off    = base - img_lo * NCELL;   // 0..48

    if (tid < NSPAN) s_mask[tid] = 0u;
    __syncthreads();

    // ---- stage GT (threads 0..127) and labels (threads 128..255) ----
    if (tid < 128) {
        const unsigned g   = tid >> 5;               // image slot 0..3
        const unsigned img = img_lo + g;
        if (img < NIMG) {
            float4 b = reinterpret_cast<const float4*>(gt_boxes)[img * NGT + (tid & 31)];
            s_gtc[tid] = make_float4(fmaf(b.z, -0.5f, b.x), fmaf(b.w, -0.5f, b.y),
                                     fmaf(b.z,  0.5f, b.x), fmaf(b.w,  0.5f, b.y));
            s_ga[tid] = b.z * b.w;
        }
    } else {
        const int t = tid - 128;
        const unsigned g   = t >> 5;
        const unsigned img = img_lo + g;
        if (img < NIMG) {
            int lab = gt_labels[img * NGT + (t & 31)];
            atomicOr(&s_mask[g], 1u << lab);
        }
    }

    // ---- stage activations: 960 float4, coalesced ----
    const float4* asrc = reinterpret_cast<const float4*>(outputs) + (size_t)base * 30 / 4;
    #pragma unroll
    for (int k = 0; k < 4; ++k) {
        int i = tid + k * 256;
        if (i < CPB * 30 / 4) s_act4[i] = asrc[i];
    }
    __syncthreads();

    // ---- per-thread: one (cell, box) ----
    const int p = tid & 1;                           // box index
    const int s = tid >> 1;                          // cell slot 0..127
    const unsigned rel  = ((unsigned)(s + off) * 1339u) >> 16;   // (s+off)/49, arg<392
    const unsigned mask = s_mask[rel];
    const float2* a2 = reinterpret_cast<const float2*>(s_act4) + s * 15;

    // ---- CE, split across the box pair (each thread: 10 classes) ----
    const float2* cp = a2 + 5 + p * 5;
    float2 c0 = cp[0], c1 = cp[1], c2 = cp[2], c3 = cp[3], c4 = cp[4];
    float mxh = fmaxf(fmaxf(fmaxf(c0.x, c0.y), fmaxf(c1.x, c1.y)),
                      fmaxf(fmaxf(c2.x, c2.y), fmaxf(c3.x, c3.y)));
    mxh = fmaxf(mxh, fmaxf(c4.x, c4.y));
    const unsigned mh = mask >> (p * 10);
    float selh = ((mh & 1u)   ? c0.x : 0.f) + ((mh & 2u)   ? c0.y : 0.f)
               + ((mh & 4u)   ? c1.x : 0.f) + ((mh & 8u)   ? c1.y : 0.f)
               + ((mh & 16u)  ? c2.x : 0.f) + ((mh & 32u)  ? c2.y : 0.f)
               + ((mh & 64u)  ? c3.x : 0.f) + ((mh & 128u) ? c3.y : 0.f)
               + ((mh & 256u) ? c4.x : 0.f) + ((mh & 512u) ? c4.y : 0.f);
    const float mx = fmaxf(mxh, __shfl_xor(mxh, 1));
    float ssh = __expf(c0.x - mx) + __expf(c0.y - mx)
              + __expf(c1.x - mx) + __expf(c1.y - mx)
              + __expf(c2.x - mx) + __expf(c2.y - mx)
              + __expf(c3.x - mx) + __expf(c3.y - mx)
              + __expf(c4.x - mx) + __expf(c4.y - mx);
    const float ssum = ssh + __shfl_xor(ssh, 1);
    const float sel  = selh + __shfl_xor(selh, 1);
    const float ce = (float)__popc(mask) * (mx + __logf(ssum)) - sel;

    // ---- my box: floats [5p .. 5p+4] of the cell record ----
    float2 A = a2[2 * p], Bv = a2[2 * p + 1], Cv = a2[2 * p + 2];
    const float cx = p ? A.y  : A.x;
    const float cy = p ? Bv.x : A.y;
    const float w  = p ? Bv.y : Bv.x;
    const float h  = p ? Cv.x : Bv.y;
    const float cf = p ? Cv.y : Cv.x;

    const float px1 = fmaf(w, -0.5f, cx), py1 = fmaf(h, -0.5f, cy);
    const float px2 = fmaf(w,  0.5f, cx), py2 = fmaf(h,  0.5f, cy);
    const float pae = w * h + EPS_IOU;

    // ---- IoU argmax over 32 GTs (broadcast LDS reads, unroll-2 chunks) ----
    const float4* gtc = s_gtc + rel * NGT;
    const float*  gab = s_ga  + rel * NGT;
    float bin = -1.f, bS = 1.f;
    int bi = 0;
    #pragma unroll
    for (int j = 0; j < NGT; j += 2) {
        float4 g0 = gtc[j], g1 = gtc[j + 1];
        float2 ar = *reinterpret_cast<const float2*>(gab + j);
        {
            float iw = fmaxf(fminf(px2, g0.z) - fmaxf(px1, g0.x), 0.f);
            float ih = fmaxf(fminf(py2, g0.w) - fmaxf(py1, g0.y), 0.f);
            float in = iw * ih, S = pae + ar.x;
            if (in * bS > bin * S) { bin = in; bS = S; bi = j; }
        }
        {
            float iw = fmaxf(fminf(px2, g1.z) - fmaxf(px1, g1.x), 0.f);
            float ih = fmaxf(fminf(py2, g1.w) - fmaxf(py1, g1.y), 0.f);
            float in = iw * ih, S = pae + ar.y;
            if (in * bS > bin * S) { bin = in; bS = S; bi = j + 1; }
        }
    }

    // ---- loss term for this (cell, box) ----
    float term;
    if (bin > 0.f) {
        float4 g = gtc[bi];
        const float iou = __fdividef(bin, bS - bin);
        const float dx = cx - (g.x + g.z) * 0.5f;
        const float dy = cy - (g.y + g.w) * 0.5f;
        const float dw = sqrtf(w) - sqrtf(g.z - g.x);
        const float dh = sqrtf(h) - sqrtf(g.w - g.y);
        term = LAMBDA_COORD * (dx * dx + dy * dy + dw * dw + dh * dh)
             + (cf - iou) * (cf - iou) + ce;
    } else {
        term = LAMBDA_NOOBJ * cf * cf;
    }

    // ---- block reduce -> 1 float per block ----
    float partial = term;
    #pragma unroll
    for (int o = 32; o > 0; o >>= 1)
        partial += __shfl_down(partial, o);
    if ((tid & 63) == 0) s_w[tid >> 6] = partial;
    __syncthreads();
    if (tid == 0)
        partials[blockIdx.x] = s_w[0] + s_w[1] + s_w[2] + s_w[3];
}

__global__ __launch_bounds__(256) void yolo_reduce_kernel(
    const float* __restrict__ partials, float* __restrict__ out)
{
    float s = 0.f;
    for (int i = threadIdx.x; i < NBLK; i += 256) s += partials[i];
    #pragma unroll
    for (int o = 32; o > 0; o >>= 1)
        s += __shfl_down(s, o);
    __shared__ float s_w[4];
    const int tid = threadIdx.x;
    if ((tid & 63) == 0) s_w[tid >> 6] = s;
    __syncthreads();
    if (tid == 0)
        out[0] = (s_w[0] + s_w[1] + s_w[2] + s_w[3]) * (1.0f / (float)NIMG);
}

extern "C" void kernel_launch(void* const* d_in, const int* in_sizes, int n_in,
                              void* d_out, int out_size, void* d_ws, size_t ws_size,
                              hipStream_t stream) {
    const float* outputs   = (const float*)d_in[0];
    const float* gt_boxes  = (const float*)d_in[1];
    const int*   gt_labels = (const int*)d_in[2];
    float* out      = (float*)d_out;
    float* partials = (float*)d_ws;          // NBLK floats = 12.5 KB

    yolo_main_kernel<<<NBLK, 256, 0, stream>>>(outputs, gt_boxes, gt_labels, partials);
    yolo_reduce_kernel<<<1, 256, 0, stream>>>(partials, out);
}